// Round 1
// baseline (1196.345 us; speedup 1.0000x reference)
//
#include <hip/hip_runtime.h>
#include <hip/hip_bf16.h>
#include <cmath>

// ---------------- problem constants ----------------
constexpr int B_ = 16, N_ = 577, C_ = 768, H_ = 12, D_ = 64, HID_ = 3072;
constexpr int ROWS_ = B_ * N_;   // 9232
constexpr int BH_ = B_ * H_;     // 192

typedef __attribute__((ext_vector_type(8))) __bf16 bf16x8;
typedef __attribute__((ext_vector_type(4))) float f32x4;

#define DEVI __device__ __forceinline__

DEVI unsigned short f2bf(float f) {
  unsigned u = __float_as_uint(f);
  return (unsigned short)((u + 0x7fffu + ((u >> 16) & 1u)) >> 16);
}

// ---------------- f32 -> bf16 convert ----------------
__global__ __launch_bounds__(256) void cvt_kernel(const float* __restrict__ in,
                                                  unsigned short* __restrict__ out, int n) {
  for (int i = blockIdx.x * blockDim.x + threadIdx.x; i < n; i += gridDim.x * blockDim.x)
    out[i] = f2bf(in[i]);
}

// ---------------- layernorm (768 = 3*256) ----------------
__global__ __launch_bounds__(256) void ln_kernel(const float* __restrict__ x,
                                                 const float* __restrict__ g,
                                                 const float* __restrict__ be,
                                                 unsigned short* __restrict__ out) {
  int row = blockIdx.x;
  const float* xr = x + (long)row * C_;
  float v[3];
  float s = 0.f, s2 = 0.f;
#pragma unroll
  for (int j = 0; j < 3; j++) {
    int i = threadIdx.x + j * 256;
    v[j] = xr[i];
    s += v[j];
    s2 += v[j] * v[j];
  }
#pragma unroll
  for (int o = 32; o > 0; o >>= 1) {
    s += __shfl_down(s, o);
    s2 += __shfl_down(s2, o);
  }
  __shared__ float sh[8];
  int w = threadIdx.x >> 6;
  if ((threadIdx.x & 63) == 0) { sh[w] = s; sh[4 + w] = s2; }
  __syncthreads();
  s = sh[0] + sh[1] + sh[2] + sh[3];
  s2 = sh[4] + sh[5] + sh[6] + sh[7];
  float mu = s * (1.f / C_);
  float var = s2 * (1.f / C_) - mu * mu;
  float rs = rsqrtf(var + 1e-5f);
#pragma unroll
  for (int j = 0; j < 3; j++) {
    int i = threadIdx.x + j * 256;
    out[(long)row * C_ + i] = f2bf((v[j] - mu) * rs * g[i] + be[i]);
  }
}

// ---------------- softmax over rows of 577, in place (fp32) ----------------
__global__ __launch_bounds__(256) void softmax_kernel(float* __restrict__ attn) {
  long row = blockIdx.x;
  float* p = attn + row * (long)N_;
  int tid = threadIdx.x;
  float v[3];
  float m = -1e30f;
#pragma unroll
  for (int j = 0; j < 3; j++) {
    int i = tid + j * 256;
    v[j] = (i < N_) ? p[i] : -1e30f;
    m = fmaxf(m, v[j]);
  }
#pragma unroll
  for (int o = 32; o > 0; o >>= 1) m = fmaxf(m, __shfl_down(m, o));
  __shared__ float sh[8];
  int w = tid >> 6;
  if ((tid & 63) == 0) sh[w] = m;
  __syncthreads();
  m = fmaxf(fmaxf(sh[0], sh[1]), fmaxf(sh[2], sh[3]));
  float e[3];
  float s = 0.f;
#pragma unroll
  for (int j = 0; j < 3; j++) {
    int i = tid + j * 256;
    e[j] = (i < N_) ? expf(v[j] - m) : 0.f;
    s += e[j];
  }
#pragma unroll
  for (int o = 32; o > 0; o >>= 1) s += __shfl_down(s, o);
  if ((tid & 63) == 0) sh[4 + w] = s;
  __syncthreads();
  s = sh[4] + sh[5] + sh[6] + sh[7];
  float inv = 1.f / s;
#pragma unroll
  for (int j = 0; j < 3; j++) {
    int i = tid + j * 256;
    if (i < N_) p[i] = e[j] * inv;
  }
}

// ---------------- generic MFMA GEMM ----------------
// ASRC: 0 = A is bf16(ushort), 1 = A is fp32 (converted during staging)
// BLAY: 0 = B given as [K][N] row-major, 1 = B given K-major as [N][K] (i.e. B^T rows)
// EPI : 0 qkv scatter(+bias,+q scale) | 1 plain f32 store | 2 ctx bf16 scatter
//       3 f32 +bias+resid | 4 bf16 gelu(+bias) | 5 f32 +bias+resid (same as 3)
template <int ASRC, int BLAY, int EPI>
__global__ __launch_bounds__(256) void gemm_kernel(
    const void* __restrict__ Ap, int lda, int batchA,
    const unsigned short* __restrict__ Bp, int ldb, int batchB,
    int M, int N, int K,
    void* __restrict__ outp, int batchOut,
    const float* __restrict__ bias,
    const float* __restrict__ resid) {
  __shared__ unsigned short As[64][40];
  __shared__ unsigned short Bs[64][40];  // Bs[col][k]
  const int tid = threadIdx.x;
  const int bz = blockIdx.z;
  const long m0 = (long)blockIdx.y * 64;
  const long n0 = (long)blockIdx.x * 64;

  const unsigned short* A16 = (const unsigned short*)Ap + (long)bz * batchA;
  const float* A32 = (const float*)Ap + (long)bz * batchA;
  const unsigned short* Bg = Bp + (long)bz * batchB;

  const int lane = tid & 63;
  const int wave = tid >> 6;
  const int wr = (wave >> 1) * 32, wc = (wave & 1) * 32;
  const int l15 = lane & 15, l4 = lane >> 4;

  f32x4 acc[2][2];
#pragma unroll
  for (int i = 0; i < 2; i++)
#pragma unroll
    for (int j = 0; j < 2; j++) acc[i][j] = f32x4{0.f, 0.f, 0.f, 0.f};

  const int ar = tid >> 2, akc = (tid & 3) * 8;

  for (int k0 = 0; k0 < K; k0 += 32) {
    // ---- stage A tile [64][32] ----
    {
      alignas(16) unsigned short tmp[8];
      long gr = m0 + ar;
      int gk = k0 + akc;
      if (gr < M) {
        if constexpr (ASRC == 0) {
          if (gk + 8 <= K) {
            *(int4*)tmp = *(const int4*)(A16 + gr * (long)lda + gk);
          } else {
#pragma unroll
            for (int j = 0; j < 8; j++) tmp[j] = (gk + j < K) ? A16[gr * (long)lda + gk + j] : 0;
          }
        } else {
#pragma unroll
          for (int j = 0; j < 8; j++)
            tmp[j] = (gk + j < K) ? f2bf(A32[gr * (long)lda + gk + j]) : 0;
        }
      } else {
#pragma unroll
        for (int j = 0; j < 8; j++) tmp[j] = 0;
      }
      *(int4*)&As[ar][akc] = *(const int4*)tmp;
    }
    // ---- stage B tile -> Bs[col][k] ----
    if constexpr (BLAY == 1) {
      alignas(16) unsigned short tmp[8];
      long gc = n0 + ar;
      int gk = k0 + akc;
      if (gc < N) {
        if (gk + 8 <= K) {
          *(int4*)tmp = *(const int4*)(Bg + gc * (long)ldb + gk);
        } else {
#pragma unroll
          for (int j = 0; j < 8; j++) tmp[j] = (gk + j < K) ? Bg[gc * (long)ldb + gk + j] : 0;
        }
      } else {
#pragma unroll
        for (int j = 0; j < 8; j++) tmp[j] = 0;
      }
      *(int4*)&Bs[ar][akc] = *(const int4*)tmp;
    } else {
      alignas(16) unsigned short tmp[8];
      int kk = tid >> 3;
      int cbase = (tid & 7) * 8;
      long gc0 = n0 + cbase;
      int gk = k0 + kk;
      if (gk < K) {
        if (gc0 + 8 <= N) {
          *(int4*)tmp = *(const int4*)(Bg + (long)gk * ldb + gc0);
        } else {
#pragma unroll
          for (int j = 0; j < 8; j++) tmp[j] = (gc0 + j < N) ? Bg[(long)gk * ldb + gc0 + j] : 0;
        }
      } else {
#pragma unroll
        for (int j = 0; j < 8; j++) tmp[j] = 0;
      }
#pragma unroll
      for (int j = 0; j < 8; j++) Bs[cbase + j][kk] = tmp[j];
    }
    __syncthreads();
    bf16x8 a0 = *(const bf16x8*)&As[wr + l15][l4 * 8];
    bf16x8 a1 = *(const bf16x8*)&As[wr + 16 + l15][l4 * 8];
    bf16x8 b0 = *(const bf16x8*)&Bs[wc + l15][l4 * 8];
    bf16x8 b1 = *(const bf16x8*)&Bs[wc + 16 + l15][l4 * 8];
    acc[0][0] = __builtin_amdgcn_mfma_f32_16x16x32_bf16(a0, b0, acc[0][0], 0, 0, 0);
    acc[0][1] = __builtin_amdgcn_mfma_f32_16x16x32_bf16(a0, b1, acc[0][1], 0, 0, 0);
    acc[1][0] = __builtin_amdgcn_mfma_f32_16x16x32_bf16(a1, b0, acc[1][0], 0, 0, 0);
    acc[1][1] = __builtin_amdgcn_mfma_f32_16x16x32_bf16(a1, b1, acc[1][1], 0, 0, 0);
    __syncthreads();
  }

  // ---- epilogue ----
#pragma unroll
  for (int mf = 0; mf < 2; mf++)
#pragma unroll
    for (int nf = 0; nf < 2; nf++)
#pragma unroll
      for (int r = 0; r < 4; r++) {
        long row = m0 + wr + mf * 16 + l4 * 4 + r;
        long col = n0 + wc + nf * 16 + l15;
        if (row >= M || col >= N) continue;
        float v = acc[mf][nf][r];
        if constexpr (EPI == 0) {
          v += bias[col];
          int which = (int)col / C_;
          int rem = (int)col % C_;
          int h = rem >> 6, d = rem & 63;
          int b = (int)row / N_, n = (int)row % N_;
          if (which == 0) v *= 0.125f;  // fold 1/sqrt(D) into q
          unsigned short* o = (unsigned short*)outp;
          o[(long)which * ((long)BH_ * N_ * D_) + (((long)(b * H_ + h)) * N_ + n) * D_ + d] =
              f2bf(v);
        } else if constexpr (EPI == 1) {
          float* o = (float*)outp + (long)bz * batchOut;
          o[row * (long)N + col] = v;
        } else if constexpr (EPI == 2) {
          int b = bz / H_, h = bz % H_;
          unsigned short* o = (unsigned short*)outp;
          o[((long)b * N_ + row) * C_ + h * D_ + col] = f2bf(v);
        } else if constexpr (EPI == 3 || EPI == 5) {
          float* o = (float*)outp;
          long idx = row * (long)N + col;
          o[idx] = v + bias[col] + resid[idx];
        } else if constexpr (EPI == 4) {
          v += bias[col];
          float ge = 0.5f * v * (1.f + erff(v * 0.70710678118654752f));
          ((unsigned short*)outp)[row * (long)N + col] = f2bf(ge);
        }
      }
}

// ---------------- launch ----------------
extern "C" void kernel_launch(void* const* d_in, const int* in_sizes, int n_in,
                              void* d_out, int out_size, void* d_ws, size_t ws_size,
                              hipStream_t stream) {
  const float* x = (const float*)d_in[0];
  const float* w_qkv = (const float*)d_in[1];
  const float* b_qkv = (const float*)d_in[2];
  const float* w_proj = (const float*)d_in[3];
  const float* b_proj = (const float*)d_in[4];
  const float* g1 = (const float*)d_in[5];
  const float* be1 = (const float*)d_in[6];
  const float* g2 = (const float*)d_in[7];
  const float* be2 = (const float*)d_in[8];
  const float* w1 = (const float*)d_in[9];
  const float* b1 = (const float*)d_in[10];
  const float* w2 = (const float*)d_in[11];
  const float* b2 = (const float*)d_in[12];

  char* ws = (char*)d_ws;
  const size_t SZ_TOK_BF = (size_t)ROWS_ * C_ * 2;  // 14,180,352 bytes
  unsigned short* xn = (unsigned short*)(ws);        // reused as xn2 later
  unsigned short* q = (unsigned short*)(ws + SZ_TOK_BF);
  unsigned short* k = (unsigned short*)(ws + 2 * SZ_TOK_BF);
  unsigned short* v = (unsigned short*)(ws + 3 * SZ_TOK_BF);
  unsigned short* ctx = (unsigned short*)(ws + 4 * SZ_TOK_BF);
  unsigned short* h = q;  // q/k/v/ctx (4*SZ_TOK_BF) == ROWS_*HID_*2, reused for MLP hidden
  float* x1 = (float*)(ws + 5 * SZ_TOK_BF);
  unsigned short* wqkv_b = (unsigned short*)(ws + 5 * SZ_TOK_BF + (size_t)ROWS_ * C_ * 4);
  unsigned short* wproj_b = wqkv_b + (size_t)C_ * 3 * C_;
  unsigned short* w1_b = wproj_b + (size_t)C_ * C_;
  unsigned short* w2_b = w1_b + (size_t)C_ * HID_;

  float* out_x = (float*)d_out;
  float* attn = out_x + (size_t)ROWS_ * C_;

  cvt_kernel<<<2048, 256, 0, stream>>>(w_qkv, wqkv_b, C_ * 3 * C_);
  cvt_kernel<<<1024, 256, 0, stream>>>(w_proj, wproj_b, C_ * C_);
  cvt_kernel<<<2048, 256, 0, stream>>>(w1, w1_b, C_ * HID_);
  cvt_kernel<<<2048, 256, 0, stream>>>(w2, w2_b, HID_ * C_);

  ln_kernel<<<ROWS_, 256, 0, stream>>>(x, g1, be1, xn);

  {  // QKV: [9232,768] x [768,2304] -> q,k,v bf16 [B,H,N,D] (+bias, q*=0.125)
    dim3 g((3 * C_) / 64, (ROWS_ + 63) / 64, 1);
    gemm_kernel<0, 0, 0><<<g, 256, 0, stream>>>(xn, C_, 0, wqkv_b, 3 * C_, 0, ROWS_, 3 * C_, C_,
                                                q, 0, b_qkv, nullptr);
  }
  {  // scores: per (b,h) [577,64] x [64,577] -> attn raw fp32 in d_out
    dim3 g((N_ + 63) / 64, (N_ + 63) / 64, BH_);
    gemm_kernel<0, 1, 1><<<g, 256, 0, stream>>>(q, D_, N_ * D_, k, D_, N_ * D_, N_, N_, D_,
                                                attn, N_ * N_, nullptr, nullptr);
  }
  softmax_kernel<<<BH_ * N_, 256, 0, stream>>>(attn);
  {  // PV: per (b,h) [577,577] x [577,64] -> ctx bf16 [B,N,C]
    dim3 g(1, (N_ + 63) / 64, BH_);
    gemm_kernel<1, 0, 2><<<g, 256, 0, stream>>>(attn, N_, N_ * N_, v, D_, N_ * D_, N_, D_, N_,
                                                ctx, 0, nullptr, nullptr);
  }
  {  // proj: [9232,768] x [768,768] + b_proj + x -> x1 fp32
    dim3 g(C_ / 64, (ROWS_ + 63) / 64, 1);
    gemm_kernel<0, 0, 3><<<g, 256, 0, stream>>>(ctx, C_, 0, wproj_b, C_, 0, ROWS_, C_, C_, x1, 0,
                                                b_proj, x);
  }
  ln_kernel<<<ROWS_, 256, 0, stream>>>(x1, g2, be2, xn);
  {  // mlp1: [9232,768] x [768,3072] + b1, exact GELU -> h bf16
    dim3 g(HID_ / 64, (ROWS_ + 63) / 64, 1);
    gemm_kernel<0, 0, 4><<<g, 256, 0, stream>>>(xn, C_, 0, w1_b, HID_, 0, ROWS_, HID_, C_, h, 0,
                                                b1, nullptr);
  }
  {  // mlp2: [9232,3072] x [3072,768] + b2 + x1 -> d_out (x part)
    dim3 g(C_ / 64, (ROWS_ + 63) / 64, 1);
    gemm_kernel<0, 0, 5><<<g, 256, 0, stream>>>(h, HID_, 0, w2_b, C_, 0, ROWS_, C_, HID_, out_x,
                                                0, b2, x1);
  }
}

// Round 2
// 1095.911 us; speedup vs baseline: 1.0916x; 1.0916x over previous
//
#include <hip/hip_runtime.h>
#include <hip/hip_bf16.h>
#include <cmath>

// ---------------- problem constants ----------------
constexpr int B_ = 16, N_ = 577, C_ = 768, H_ = 12, D_ = 64, HID_ = 3072;
constexpr int ROWS_ = B_ * N_;   // 9232
constexpr int BH_ = B_ * H_;     // 192
constexpr int KVT_ = (N_ + 63) / 64;  // 10 kv tiles

typedef __attribute__((ext_vector_type(8))) __bf16 bf16x8;
typedef __attribute__((ext_vector_type(4))) float f32x4;

#define DEVI __device__ __forceinline__

DEVI unsigned short f2bf(float f) {
  unsigned u = __float_as_uint(f);
  return (unsigned short)((u + 0x7fffu + ((u >> 16) & 1u)) >> 16);
}

// ---------------- f32 -> bf16 convert ----------------
__global__ __launch_bounds__(256) void cvt_kernel(const float* __restrict__ in,
                                                  unsigned short* __restrict__ out, int n) {
  for (int i = blockIdx.x * blockDim.x + threadIdx.x; i < n; i += gridDim.x * blockDim.x)
    out[i] = f2bf(in[i]);
}

// ---------------- layernorm (768 = 3*256) ----------------
__global__ __launch_bounds__(256) void ln_kernel(const float* __restrict__ x,
                                                 const float* __restrict__ g,
                                                 const float* __restrict__ be,
                                                 unsigned short* __restrict__ out) {
  int row = blockIdx.x;
  const float* xr = x + (long)row * C_;
  float v[3];
  float s = 0.f, s2 = 0.f;
#pragma unroll
  for (int j = 0; j < 3; j++) {
    int i = threadIdx.x + j * 256;
    v[j] = xr[i];
    s += v[j];
    s2 += v[j] * v[j];
  }
#pragma unroll
  for (int o = 32; o > 0; o >>= 1) {
    s += __shfl_down(s, o);
    s2 += __shfl_down(s2, o);
  }
  __shared__ float sh[8];
  int w = threadIdx.x >> 6;
  if ((threadIdx.x & 63) == 0) { sh[w] = s; sh[4 + w] = s2; }
  __syncthreads();
  s = sh[0] + sh[1] + sh[2] + sh[3];
  s2 = sh[4] + sh[5] + sh[6] + sh[7];
  float mu = s * (1.f / C_);
  float var = s2 * (1.f / C_) - mu * mu;
  float rs = rsqrtf(var + 1e-5f);
#pragma unroll
  for (int j = 0; j < 3; j++) {
    int i = threadIdx.x + j * 256;
    out[(long)row * C_ + i] = f2bf((v[j] - mu) * rs * g[i] + be[i]);
  }
}

// ---------------- fused attention: S = qk^T, softmax, P write, ctx = P·V ----
// q,k: [BH][N][D] bf16 (q pre-scaled by 1/8); vt: [BH][D][N] bf16
// attn out: [BH][N][N] fp32 (d_out region); ctx out: [B][N][C] bf16
__global__ __launch_bounds__(256) void attn_kernel(
    const unsigned short* __restrict__ qg,
    const unsigned short* __restrict__ kg,
    const unsigned short* __restrict__ vt,
    float* __restrict__ attn,
    unsigned short* __restrict__ ctx) {
  __shared__ unsigned short Ps[4][16][72];
  const int bh = blockIdx.y;
  const int b = bh / H_, h = bh % H_;
  const int tid = threadIdx.x;
  const int wave = tid >> 6, lane = tid & 63;
  const int l15 = lane & 15, l4 = lane >> 4;
  const int q0 = blockIdx.x * 64 + wave * 16;  // this wave's q-row base

  const unsigned short* Qh = qg + (long)bh * N_ * D_;
  const unsigned short* Kh = kg + (long)bh * N_ * D_;
  const unsigned short* Vth = vt + (long)bh * D_ * N_;

  // Q A-frags: row q = q0 + l15, k(d) = ks*32 + l4*8 + j  (held for whole kernel)
  int qrow = q0 + l15;
  int qrc = qrow < N_ ? qrow : N_ - 1;
  bf16x8 qa[2];
  qa[0] = *(const bf16x8*)(Qh + (long)qrc * D_ + l4 * 8);
  qa[1] = *(const bf16x8*)(Qh + (long)qrc * D_ + 32 + l4 * 8);

  float m_run[4], l_run[4];
#pragma unroll
  for (int r = 0; r < 4; r++) { m_run[r] = -1e30f; l_run[r] = 0.f; }

  // ---------- pass 1: row stats ----------
  for (int kt = 0; kt < KVT_; kt++) {
    const int kv0 = kt * 64;
    f32x4 s[4];
#pragma unroll
    for (int nf = 0; nf < 4; nf++) {
      s[nf] = f32x4{0.f, 0.f, 0.f, 0.f};
      int kvcol = kv0 + nf * 16 + l15;
      int kvc = kvcol < N_ ? kvcol : N_ - 1;
      bf16x8 b0 = *(const bf16x8*)(Kh + (long)kvc * D_ + l4 * 8);
      bf16x8 b1 = *(const bf16x8*)(Kh + (long)kvc * D_ + 32 + l4 * 8);
      s[nf] = __builtin_amdgcn_mfma_f32_16x16x32_bf16(qa[0], b0, s[nf], 0, 0, 0);
      s[nf] = __builtin_amdgcn_mfma_f32_16x16x32_bf16(qa[1], b1, s[nf], 0, 0, 0);
      if (kvcol >= N_) s[nf] = f32x4{-1e30f, -1e30f, -1e30f, -1e30f};
    }
#pragma unroll
    for (int r = 0; r < 4; r++) {
      float mt = fmaxf(fmaxf(s[0][r], s[1][r]), fmaxf(s[2][r], s[3][r]));
#pragma unroll
      for (int o = 1; o < 16; o <<= 1) mt = fmaxf(mt, __shfl_xor(mt, o));
      float mn = fmaxf(m_run[r], mt);
      float lt = expf(s[0][r] - mn) + expf(s[1][r] - mn) + expf(s[2][r] - mn) +
                 expf(s[3][r] - mn);
#pragma unroll
      for (int o = 1; o < 16; o <<= 1) lt += __shfl_xor(lt, o);
      l_run[r] = l_run[r] * expf(m_run[r] - mn) + lt;
      m_run[r] = mn;
    }
  }

  float inv_l[4];
#pragma unroll
  for (int r = 0; r < 4; r++) inv_l[r] = 1.f / l_run[r];

  // ---------- pass 2: P write + PV ----------
  f32x4 cacc[4];
#pragma unroll
  for (int nf = 0; nf < 4; nf++) cacc[nf] = f32x4{0.f, 0.f, 0.f, 0.f};

  for (int kt = 0; kt < KVT_; kt++) {
    const int kv0 = kt * 64;
    f32x4 s[4];
#pragma unroll
    for (int nf = 0; nf < 4; nf++) {
      s[nf] = f32x4{0.f, 0.f, 0.f, 0.f};
      int kvcol = kv0 + nf * 16 + l15;
      int kvc = kvcol < N_ ? kvcol : N_ - 1;
      bf16x8 b0 = *(const bf16x8*)(Kh + (long)kvc * D_ + l4 * 8);
      bf16x8 b1 = *(const bf16x8*)(Kh + (long)kvc * D_ + 32 + l4 * 8);
      s[nf] = __builtin_amdgcn_mfma_f32_16x16x32_bf16(qa[0], b0, s[nf], 0, 0, 0);
      s[nf] = __builtin_amdgcn_mfma_f32_16x16x32_bf16(qa[1], b1, s[nf], 0, 0, 0);
      if (kvcol >= N_) s[nf] = f32x4{-1e30f, -1e30f, -1e30f, -1e30f};
    }
    // P = exp(s - m)/l : write fp32 to d_out, bf16 to LDS for the PV A-frag
#pragma unroll
    for (int nf = 0; nf < 4; nf++) {
      int kvcol = kv0 + nf * 16 + l15;
#pragma unroll
      for (int r = 0; r < 4; r++) {
        float p = expf(s[nf][r] - m_run[r]) * inv_l[r];
        int qv = q0 + l4 * 4 + r;
        if (qv < N_ && kvcol < N_)
          attn[((long)bh * N_ + qv) * N_ + kvcol] = p;
        Ps[wave][l4 * 4 + r][nf * 16 + l15] = f2bf(p);
      }
    }
    // PV: ctx[q][d] += P[q][kv] * V[kv][d];  A from LDS, B direct from vt
#pragma unroll
    for (int ks = 0; ks < 2; ks++) {
      bf16x8 pa = *(const bf16x8*)&Ps[wave][l15][ks * 32 + l4 * 8];
#pragma unroll
      for (int nf = 0; nf < 4; nf++) {
        bf16x8 vb = *(const bf16x8*)(Vth + (long)(nf * 16 + l15) * N_ + kv0 + ks * 32 + l4 * 8);
        cacc[nf] = __builtin_amdgcn_mfma_f32_16x16x32_bf16(pa, vb, cacc[nf], 0, 0, 0);
      }
    }
  }

  // ---------- ctx write ----------
#pragma unroll
  for (int nf = 0; nf < 4; nf++)
#pragma unroll
    for (int r = 0; r < 4; r++) {
      int qv = q0 + l4 * 4 + r;
      if (qv >= N_) continue;
      int d = nf * 16 + l15;
      ctx[((long)b * N_ + qv) * C_ + h * D_ + d] = f2bf(cacc[nf][r]);
    }
}

// ---------------- generic MFMA GEMM ----------------
// EPI : 0 qkv scatter(+bias,+q scale, V transposed) | 3 f32 +bias+resid
//       4 bf16 gelu(+bias) | 5 f32 +bias+resid
template <int EPI>
__global__ __launch_bounds__(256) void gemm_kernel(
    const unsigned short* __restrict__ Ap, int lda,
    const unsigned short* __restrict__ Bp, int ldb,
    int M, int N, int K,
    void* __restrict__ outp,
    const float* __restrict__ bias,
    const float* __restrict__ resid) {
  __shared__ unsigned short As[64][40];
  __shared__ unsigned short Bs[64][40];  // Bs[col][k]
  const int tid = threadIdx.x;
  const long m0 = (long)blockIdx.y * 64;
  const long n0 = (long)blockIdx.x * 64;

  const int lane = tid & 63;
  const int wave = tid >> 6;
  const int wr = (wave >> 1) * 32, wc = (wave & 1) * 32;
  const int l15 = lane & 15, l4 = lane >> 4;

  f32x4 acc[2][2];
#pragma unroll
  for (int i = 0; i < 2; i++)
#pragma unroll
    for (int j = 0; j < 2; j++) acc[i][j] = f32x4{0.f, 0.f, 0.f, 0.f};

  const int ar = tid >> 2, akc = (tid & 3) * 8;

  for (int k0 = 0; k0 < K; k0 += 32) {
    {  // stage A tile [64][32]
      alignas(16) unsigned short tmp[8];
      long gr = m0 + ar;
      int gk = k0 + akc;
      if (gr < M) {
        *(int4*)tmp = *(const int4*)(Ap + gr * (long)lda + gk);
      } else {
#pragma unroll
        for (int j = 0; j < 8; j++) tmp[j] = 0;
      }
      *(int4*)&As[ar][akc] = *(const int4*)tmp;
    }
    {  // stage B tile [K][N] row-major -> Bs[col][k]
      alignas(16) unsigned short tmp[8];
      int kk = tid >> 3;
      int cbase = (tid & 7) * 8;
      long gc0 = n0 + cbase;
      int gk = k0 + kk;
      *(int4*)tmp = *(const int4*)(Bp + (long)gk * ldb + gc0);
#pragma unroll
      for (int j = 0; j < 8; j++) Bs[cbase + j][kk] = tmp[j];
    }
    __syncthreads();
    bf16x8 a0 = *(const bf16x8*)&As[wr + l15][l4 * 8];
    bf16x8 a1 = *(const bf16x8*)&As[wr + 16 + l15][l4 * 8];
    bf16x8 b0 = *(const bf16x8*)&Bs[wc + l15][l4 * 8];
    bf16x8 b1 = *(const bf16x8*)&Bs[wc + 16 + l15][l4 * 8];
    acc[0][0] = __builtin_amdgcn_mfma_f32_16x16x32_bf16(a0, b0, acc[0][0], 0, 0, 0);
    acc[0][1] = __builtin_amdgcn_mfma_f32_16x16x32_bf16(a0, b1, acc[0][1], 0, 0, 0);
    acc[1][0] = __builtin_amdgcn_mfma_f32_16x16x32_bf16(a1, b0, acc[1][0], 0, 0, 0);
    acc[1][1] = __builtin_amdgcn_mfma_f32_16x16x32_bf16(a1, b1, acc[1][1], 0, 0, 0);
    __syncthreads();
  }

  // ---- epilogue ----
#pragma unroll
  for (int mf = 0; mf < 2; mf++)
#pragma unroll
    for (int nf = 0; nf < 2; nf++)
#pragma unroll
      for (int r = 0; r < 4; r++) {
        long row = m0 + wr + mf * 16 + l4 * 4 + r;
        long col = n0 + wc + nf * 16 + l15;
        if (row >= M || col >= N) continue;
        float v = acc[mf][nf][r];
        if constexpr (EPI == 0) {
          v += bias[col];
          int which = (int)col / C_;
          int rem = (int)col % C_;
          int h = rem >> 6, d = rem & 63;
          int b = (int)row / N_, n = (int)row % N_;
          if (which == 0) v *= 0.125f;  // fold 1/sqrt(D) into q
          unsigned short* o = (unsigned short*)outp;
          long base = (long)which * ((long)BH_ * N_ * D_);
          long idx;
          if (which < 2)
            idx = base + (((long)(b * H_ + h)) * N_ + n) * D_ + d;  // q,k: [BH][N][D]
          else
            idx = base + (((long)(b * H_ + h)) * D_ + d) * N_ + n;  // v: [BH][D][N]
          o[idx] = f2bf(v);
        } else if constexpr (EPI == 3 || EPI == 5) {
          float* o = (float*)outp;
          long idx = row * (long)N + col;
          o[idx] = v + bias[col] + resid[idx];
        } else if constexpr (EPI == 4) {
          v += bias[col];
          float ge = 0.5f * v * (1.f + erff(v * 0.70710678118654752f));
          ((unsigned short*)outp)[row * (long)N + col] = f2bf(ge);
        }
      }
}

// ---------------- launch ----------------
extern "C" void kernel_launch(void* const* d_in, const int* in_sizes, int n_in,
                              void* d_out, int out_size, void* d_ws, size_t ws_size,
                              hipStream_t stream) {
  const float* x = (const float*)d_in[0];
  const float* w_qkv = (const float*)d_in[1];
  const float* b_qkv = (const float*)d_in[2];
  const float* w_proj = (const float*)d_in[3];
  const float* b_proj = (const float*)d_in[4];
  const float* g1 = (const float*)d_in[5];
  const float* be1 = (const float*)d_in[6];
  const float* g2 = (const float*)d_in[7];
  const float* be2 = (const float*)d_in[8];
  const float* w1 = (const float*)d_in[9];
  const float* b1 = (const float*)d_in[10];
  const float* w2 = (const float*)d_in[11];
  const float* b2 = (const float*)d_in[12];

  char* ws = (char*)d_ws;
  const size_t SZ_TOK_BF = (size_t)ROWS_ * C_ * 2;  // 14,180,352 bytes
  unsigned short* xn = (unsigned short*)(ws);        // reused as xn2 later
  unsigned short* q = (unsigned short*)(ws + SZ_TOK_BF);   // [BH][N][D]
  unsigned short* v = (unsigned short*)(ws + 3 * SZ_TOK_BF);  // [BH][D][N]
  unsigned short* ctx = (unsigned short*)(ws + 4 * SZ_TOK_BF);
  unsigned short* h = q;  // q/k/v/ctx area reused for MLP hidden
  float* x1 = (float*)(ws + 5 * SZ_TOK_BF);
  unsigned short* wqkv_b = (unsigned short*)(ws + 5 * SZ_TOK_BF + (size_t)ROWS_ * C_ * 4);
  unsigned short* wproj_b = wqkv_b + (size_t)C_ * 3 * C_;
  unsigned short* w1_b = wproj_b + (size_t)C_ * C_;
  unsigned short* w2_b = w1_b + (size_t)C_ * HID_;

  float* out_x = (float*)d_out;
  float* attn = out_x + (size_t)ROWS_ * C_;

  cvt_kernel<<<2048, 256, 0, stream>>>(w_qkv, wqkv_b, C_ * 3 * C_);
  cvt_kernel<<<1024, 256, 0, stream>>>(w_proj, wproj_b, C_ * C_);
  cvt_kernel<<<2048, 256, 0, stream>>>(w1, w1_b, C_ * HID_);
  cvt_kernel<<<2048, 256, 0, stream>>>(w2, w2_b, HID_ * C_);

  ln_kernel<<<ROWS_, 256, 0, stream>>>(x, g1, be1, xn);

  {  // QKV: [9232,768] x [768,2304] -> q,k [BH][N][D], v [BH][D][N] (+bias, q*=0.125)
    dim3 g((3 * C_) / 64, (ROWS_ + 63) / 64, 1);
    gemm_kernel<0><<<g, 256, 0, stream>>>(xn, C_, wqkv_b, 3 * C_, ROWS_, 3 * C_, C_,
                                          q, b_qkv, nullptr);
  }
  {  // fused attention: scores+softmax+PV; attn weights -> d_out, ctx -> ws
    dim3 g((N_ + 63) / 64, BH_, 1);
    attn_kernel<<<g, 256, 0, stream>>>(q, q + (size_t)BH_ * N_ * D_, v, attn, ctx);
  }
  {  // proj: [9232,768] x [768,768] + b_proj + x -> x1 fp32
    dim3 g(C_ / 64, (ROWS_ + 63) / 64, 1);
    gemm_kernel<3><<<g, 256, 0, stream>>>(ctx, C_, wproj_b, C_, ROWS_, C_, C_, x1,
                                          b_proj, x);
  }
  ln_kernel<<<ROWS_, 256, 0, stream>>>(x1, g2, be2, xn);
  {  // mlp1: [9232,768] x [768,3072] + b1, exact GELU -> h bf16
    dim3 g(HID_ / 64, (ROWS_ + 63) / 64, 1);
    gemm_kernel<4><<<g, 256, 0, stream>>>(xn, C_, w1_b, HID_, ROWS_, HID_, C_, h,
                                          b1, nullptr);
  }
  {  // mlp2: [9232,3072] x [3072,768] + b2 + x1 -> d_out (x part)
    dim3 g(C_ / 64, (ROWS_ + 63) / 64, 1);
    gemm_kernel<5><<<g, 256, 0, stream>>>(h, HID_, w2_b, C_, ROWS_, C_, HID_, out_x,
                                          b2, x1);
  }
}

// Round 3
// 1092.527 us; speedup vs baseline: 1.0950x; 1.0031x over previous
//
#include <hip/hip_runtime.h>
#include <hip/hip_bf16.h>
#include <cmath>

// ---------------- problem constants ----------------
constexpr int B_ = 16, N_ = 577, C_ = 768, H_ = 12, D_ = 64, HID_ = 3072;
constexpr int ROWS_ = B_ * N_;   // 9232
constexpr int BH_ = B_ * H_;     // 192
constexpr int KVT_ = (N_ + 63) / 64;  // 10 kv tiles
constexpr int QBLK_ = (N_ + 63) / 64; // 10 q blocks per bh

typedef __attribute__((ext_vector_type(8))) __bf16 bf16x8;
typedef __attribute__((ext_vector_type(4))) float f32x4;

#define DEVI __device__ __forceinline__

DEVI unsigned short f2bf(float f) {
  unsigned u = __float_as_uint(f);
  return (unsigned short)((u + 0x7fffu + ((u >> 16) & 1u)) >> 16);
}

// ---------------- f32 -> bf16 convert ----------------
__global__ __launch_bounds__(256) void cvt_kernel(const float* __restrict__ in,
                                                  unsigned short* __restrict__ out, int n) {
  for (int i = blockIdx.x * blockDim.x + threadIdx.x; i < n; i += gridDim.x * blockDim.x)
    out[i] = f2bf(in[i]);
}

// ---------------- layernorm (768 = 3*256) ----------------
__global__ __launch_bounds__(256) void ln_kernel(const float* __restrict__ x,
                                                 const float* __restrict__ g,
                                                 const float* __restrict__ be,
                                                 unsigned short* __restrict__ out) {
  int row = blockIdx.x;
  const float* xr = x + (long)row * C_;
  float v[3];
  float s = 0.f, s2 = 0.f;
#pragma unroll
  for (int j = 0; j < 3; j++) {
    int i = threadIdx.x + j * 256;
    v[j] = xr[i];
    s += v[j];
    s2 += v[j] * v[j];
  }
#pragma unroll
  for (int o = 32; o > 0; o >>= 1) {
    s += __shfl_down(s, o);
    s2 += __shfl_down(s2, o);
  }
  __shared__ float sh[8];
  int w = threadIdx.x >> 6;
  if ((threadIdx.x & 63) == 0) { sh[w] = s; sh[4 + w] = s2; }
  __syncthreads();
  s = sh[0] + sh[1] + sh[2] + sh[3];
  s2 = sh[4] + sh[5] + sh[6] + sh[7];
  float mu = s * (1.f / C_);
  float var = s2 * (1.f / C_) - mu * mu;
  float rs = rsqrtf(var + 1e-5f);
#pragma unroll
  for (int j = 0; j < 3; j++) {
    int i = threadIdx.x + j * 256;
    out[(long)row * C_ + i] = f2bf((v[j] - mu) * rs * g[i] + be[i]);
  }
}

// ---------------- fused attention: S = qk^T, softmax, P write, ctx = P·V ----
// q,k: [BH][N][D] bf16 (q pre-scaled by 1/8); vt: [BH][D][N] bf16
// attn out: [BH][N][N] fp32 (d_out region); ctx out: [B][N][C] bf16
// 1D grid of BH_*QBLK_ blocks, XCD-swizzled so all q-blocks of one bh share an XCD.
__global__ __launch_bounds__(256) void attn_kernel(
    const unsigned short* __restrict__ qg,
    const unsigned short* __restrict__ kg,
    const unsigned short* __restrict__ vt,
    float* __restrict__ attn,
    unsigned short* __restrict__ ctx) {
  __shared__ unsigned short Ps[4][16][72];
  // bijective XCD swizzle: nwg = 1920 = 8 * 240
  const int wgid = (blockIdx.x & 7) * (BH_ * QBLK_ / 8) + (blockIdx.x >> 3);
  const int bh = wgid / QBLK_;
  const int qb = wgid % QBLK_;
  const int b = bh / H_, h = bh % H_;
  const int tid = threadIdx.x;
  const int wave = tid >> 6, lane = tid & 63;
  const int l15 = lane & 15, l4 = lane >> 4;
  const int q0 = qb * 64 + wave * 16;  // this wave's q-row base

  const unsigned short* Qh = qg + (long)bh * N_ * D_;
  const unsigned short* Kh = kg + (long)bh * N_ * D_;
  const unsigned short* Vth = vt + (long)bh * D_ * N_;

  // Q A-frags: row q = q0 + l15, k(d) = ks*32 + l4*8 + j  (held for whole kernel)
  int qrow = q0 + l15;
  int qrc = qrow < N_ ? qrow : N_ - 1;
  bf16x8 qa[2];
  qa[0] = *(const bf16x8*)(Qh + (long)qrc * D_ + l4 * 8);
  qa[1] = *(const bf16x8*)(Qh + (long)qrc * D_ + 32 + l4 * 8);

  float m_run[4], l_run[4];
#pragma unroll
  for (int r = 0; r < 4; r++) { m_run[r] = -1e30f; l_run[r] = 0.f; }

  // ---------- pass 1: row stats ----------
  for (int kt = 0; kt < KVT_; kt++) {
    const int kv0 = kt * 64;
    f32x4 s[4];
#pragma unroll
    for (int nf = 0; nf < 4; nf++) {
      s[nf] = f32x4{0.f, 0.f, 0.f, 0.f};
      int kvcol = kv0 + nf * 16 + l15;
      int kvc = kvcol < N_ ? kvcol : N_ - 1;
      bf16x8 b0 = *(const bf16x8*)(Kh + (long)kvc * D_ + l4 * 8);
      bf16x8 b1 = *(const bf16x8*)(Kh + (long)kvc * D_ + 32 + l4 * 8);
      s[nf] = __builtin_amdgcn_mfma_f32_16x16x32_bf16(qa[0], b0, s[nf], 0, 0, 0);
      s[nf] = __builtin_amdgcn_mfma_f32_16x16x32_bf16(qa[1], b1, s[nf], 0, 0, 0);
      if (kvcol >= N_) s[nf] = f32x4{-1e30f, -1e30f, -1e30f, -1e30f};
    }
#pragma unroll
    for (int r = 0; r < 4; r++) {
      float mt = fmaxf(fmaxf(s[0][r], s[1][r]), fmaxf(s[2][r], s[3][r]));
#pragma unroll
      for (int o = 1; o < 16; o <<= 1) mt = fmaxf(mt, __shfl_xor(mt, o));
      float mn = fmaxf(m_run[r], mt);
      float lt = __expf(s[0][r] - mn) + __expf(s[1][r] - mn) + __expf(s[2][r] - mn) +
                 __expf(s[3][r] - mn);
#pragma unroll
      for (int o = 1; o < 16; o <<= 1) lt += __shfl_xor(lt, o);
      l_run[r] = l_run[r] * __expf(m_run[r] - mn) + lt;
      m_run[r] = mn;
    }
  }

  float inv_l[4];
#pragma unroll
  for (int r = 0; r < 4; r++) inv_l[r] = 1.f / l_run[r];

  // ---------- pass 2: P write + PV ----------
  f32x4 cacc[4];
#pragma unroll
  for (int nf = 0; nf < 4; nf++) cacc[nf] = f32x4{0.f, 0.f, 0.f, 0.f};

  for (int kt = 0; kt < KVT_; kt++) {
    const int kv0 = kt * 64;
    f32x4 s[4];
#pragma unroll
    for (int nf = 0; nf < 4; nf++) {
      s[nf] = f32x4{0.f, 0.f, 0.f, 0.f};
      int kvcol = kv0 + nf * 16 + l15;
      int kvc = kvcol < N_ ? kvcol : N_ - 1;
      bf16x8 b0 = *(const bf16x8*)(Kh + (long)kvc * D_ + l4 * 8);
      bf16x8 b1 = *(const bf16x8*)(Kh + (long)kvc * D_ + 32 + l4 * 8);
      s[nf] = __builtin_amdgcn_mfma_f32_16x16x32_bf16(qa[0], b0, s[nf], 0, 0, 0);
      s[nf] = __builtin_amdgcn_mfma_f32_16x16x32_bf16(qa[1], b1, s[nf], 0, 0, 0);
      if (kvcol >= N_) s[nf] = f32x4{-1e30f, -1e30f, -1e30f, -1e30f};
    }
    // P = exp(s - m)/l : write fp32 to d_out, bf16 to LDS for the PV A-frag
#pragma unroll
    for (int nf = 0; nf < 4; nf++) {
      int kvcol = kv0 + nf * 16 + l15;
#pragma unroll
      for (int r = 0; r < 4; r++) {
        float p = __expf(s[nf][r] - m_run[r]) * inv_l[r];
        int qv = q0 + l4 * 4 + r;
        if (qv < N_ && kvcol < N_)
          attn[((long)bh * N_ + qv) * N_ + kvcol] = p;
        Ps[wave][l4 * 4 + r][nf * 16 + l15] = f2bf(p);
      }
    }
    // PV: ctx[q][d] += P[q][kv] * V[kv][d];  A from LDS, B direct from vt
#pragma unroll
    for (int ks = 0; ks < 2; ks++) {
      bf16x8 pa = *(const bf16x8*)&Ps[wave][l15][ks * 32 + l4 * 8];
#pragma unroll
      for (int nf = 0; nf < 4; nf++) {
        bf16x8 vb = *(const bf16x8*)(Vth + (long)(nf * 16 + l15) * N_ + kv0 + ks * 32 + l4 * 8);
        cacc[nf] = __builtin_amdgcn_mfma_f32_16x16x32_bf16(pa, vb, cacc[nf], 0, 0, 0);
      }
    }
  }

  // ---------- ctx write ----------
#pragma unroll
  for (int nf = 0; nf < 4; nf++)
#pragma unroll
    for (int r = 0; r < 4; r++) {
      int qv = q0 + l4 * 4 + r;
      if (qv >= N_) continue;
      int d = nf * 16 + l15;
      ctx[((long)b * N_ + qv) * C_ + h * D_ + d] = f2bf(cacc[nf][r]);
    }
}

// ---------------- generic MFMA GEMM ----------------
// EPI : 0 qkv scatter(+bias,+q scale, V transposed) | 3 f32 +bias+resid
//       4 bf16 gelu(+bias) | 5 f32 +bias+resid
template <int EPI>
__global__ __launch_bounds__(256) void gemm_kernel(
    const unsigned short* __restrict__ Ap, int lda,
    const unsigned short* __restrict__ Bp, int ldb,
    int M, int N, int K,
    void* __restrict__ outp,
    const float* __restrict__ bias,
    const float* __restrict__ resid) {
  __shared__ unsigned short As[64][40];
  __shared__ unsigned short Bs[64][40];  // Bs[col][k]
  const int tid = threadIdx.x;
  const long m0 = (long)blockIdx.y * 64;
  const long n0 = (long)blockIdx.x * 64;

  const int lane = tid & 63;
  const int wave = tid >> 6;
  const int wr = (wave >> 1) * 32, wc = (wave & 1) * 32;
  const int l15 = lane & 15, l4 = lane >> 4;

  f32x4 acc[2][2];
#pragma unroll
  for (int i = 0; i < 2; i++)
#pragma unroll
    for (int j = 0; j < 2; j++) acc[i][j] = f32x4{0.f, 0.f, 0.f, 0.f};

  const int ar = tid >> 2, akc = (tid & 3) * 8;

  for (int k0 = 0; k0 < K; k0 += 32) {
    {  // stage A tile [64][32]
      alignas(16) unsigned short tmp[8];
      long gr = m0 + ar;
      int gk = k0 + akc;
      if (gr < M) {
        *(int4*)tmp = *(const int4*)(Ap + gr * (long)lda + gk);
      } else {
#pragma unroll
        for (int j = 0; j < 8; j++) tmp[j] = 0;
      }
      *(int4*)&As[ar][akc] = *(const int4*)tmp;
    }
    {  // stage B tile [K][N] row-major -> Bs[col][k]
      alignas(16) unsigned short tmp[8];
      int kk = tid >> 3;
      int cbase = (tid & 7) * 8;
      long gc0 = n0 + cbase;
      int gk = k0 + kk;
      *(int4*)tmp = *(const int4*)(Bp + (long)gk * ldb + gc0);
#pragma unroll
      for (int j = 0; j < 8; j++) Bs[cbase + j][kk] = tmp[j];
    }
    __syncthreads();
    bf16x8 a0 = *(const bf16x8*)&As[wr + l15][l4 * 8];
    bf16x8 a1 = *(const bf16x8*)&As[wr + 16 + l15][l4 * 8];
    bf16x8 b0 = *(const bf16x8*)&Bs[wc + l15][l4 * 8];
    bf16x8 b1 = *(const bf16x8*)&Bs[wc + 16 + l15][l4 * 8];
    acc[0][0] = __builtin_amdgcn_mfma_f32_16x16x32_bf16(a0, b0, acc[0][0], 0, 0, 0);
    acc[0][1] = __builtin_amdgcn_mfma_f32_16x16x32_bf16(a0, b1, acc[0][1], 0, 0, 0);
    acc[1][0] = __builtin_amdgcn_mfma_f32_16x16x32_bf16(a1, b0, acc[1][0], 0, 0, 0);
    acc[1][1] = __builtin_amdgcn_mfma_f32_16x16x32_bf16(a1, b1, acc[1][1], 0, 0, 0);
    __syncthreads();
  }

  // ---- epilogue ----
#pragma unroll
  for (int mf = 0; mf < 2; mf++)
#pragma unroll
    for (int nf = 0; nf < 2; nf++)
#pragma unroll
      for (int r = 0; r < 4; r++) {
        long row = m0 + wr + mf * 16 + l4 * 4 + r;
        long col = n0 + wc + nf * 16 + l15;
        if (row >= M || col >= N) continue;
        float v = acc[mf][nf][r];
        if constexpr (EPI == 0) {
          v += bias[col];
          int which = (int)col / C_;
          int rem = (int)col % C_;
          int h = rem >> 6, d = rem & 63;
          int b = (int)row / N_, n = (int)row % N_;
          if (which == 0) v *= 0.125f;  // fold 1/sqrt(D) into q
          unsigned short* o = (unsigned short*)outp;
          long base = (long)which * ((long)BH_ * N_ * D_);
          long idx;
          if (which < 2)
            idx = base + (((long)(b * H_ + h)) * N_ + n) * D_ + d;  // q,k: [BH][N][D]
          else
            idx = base + (((long)(b * H_ + h)) * D_ + d) * N_ + n;  // v: [BH][D][N]
          o[idx] = f2bf(v);
        } else if constexpr (EPI == 3 || EPI == 5) {
          float* o = (float*)outp;
          long idx = row * (long)N + col;
          o[idx] = v + bias[col] + resid[idx];
        } else if constexpr (EPI == 4) {
          v += bias[col];
          float ge = 0.5f * v * (1.f + erff(v * 0.70710678118654752f));
          ((unsigned short*)outp)[row * (long)N + col] = f2bf(ge);
        }
      }
}

// ---------------- launch ----------------
extern "C" void kernel_launch(void* const* d_in, const int* in_sizes, int n_in,
                              void* d_out, int out_size, void* d_ws, size_t ws_size,
                              hipStream_t stream) {
  const float* x = (const float*)d_in[0];
  const float* w_qkv = (const float*)d_in[1];
  const float* b_qkv = (const float*)d_in[2];
  const float* w_proj = (const float*)d_in[3];
  const float* b_proj = (const float*)d_in[4];
  const float* g1 = (const float*)d_in[5];
  const float* be1 = (const float*)d_in[6];
  const float* g2 = (const float*)d_in[7];
  const float* be2 = (const float*)d_in[8];
  const float* w1 = (const float*)d_in[9];
  const float* b1 = (const float*)d_in[10];
  const float* w2 = (const float*)d_in[11];
  const float* b2 = (const float*)d_in[12];

  char* ws = (char*)d_ws;
  const size_t SZ_TOK_BF = (size_t)ROWS_ * C_ * 2;  // 14,180,352 bytes
  unsigned short* xn = (unsigned short*)(ws);        // reused as xn2 later
  unsigned short* q = (unsigned short*)(ws + SZ_TOK_BF);   // [BH][N][D]
  unsigned short* v = (unsigned short*)(ws + 3 * SZ_TOK_BF);  // [BH][D][N]
  unsigned short* ctx = (unsigned short*)(ws + 4 * SZ_TOK_BF);
  unsigned short* h = q;  // q/k/v/ctx area reused for MLP hidden
  float* x1 = (float*)(ws + 5 * SZ_TOK_BF);
  unsigned short* wqkv_b = (unsigned short*)(ws + 5 * SZ_TOK_BF + (size_t)ROWS_ * C_ * 4);
  unsigned short* wproj_b = wqkv_b + (size_t)C_ * 3 * C_;
  unsigned short* w1_b = wproj_b + (size_t)C_ * C_;
  unsigned short* w2_b = w1_b + (size_t)C_ * HID_;

  float* out_x = (float*)d_out;
  float* attn = out_x + (size_t)ROWS_ * C_;

  cvt_kernel<<<2048, 256, 0, stream>>>(w_qkv, wqkv_b, C_ * 3 * C_);
  cvt_kernel<<<1024, 256, 0, stream>>>(w_proj, wproj_b, C_ * C_);
  cvt_kernel<<<2048, 256, 0, stream>>>(w1, w1_b, C_ * HID_);
  cvt_kernel<<<2048, 256, 0, stream>>>(w2, w2_b, HID_ * C_);

  ln_kernel<<<ROWS_, 256, 0, stream>>>(x, g1, be1, xn);

  {  // QKV: [9232,768] x [768,2304] -> q,k [BH][N][D], v [BH][D][N] (+bias, q*=0.125)
    dim3 g((3 * C_) / 64, (ROWS_ + 63) / 64, 1);
    gemm_kernel<0><<<g, 256, 0, stream>>>(xn, C_, wqkv_b, 3 * C_, ROWS_, 3 * C_, C_,
                                          q, b_qkv, nullptr);
  }
  {  // fused attention: scores+softmax+PV; attn weights -> d_out, ctx -> ws
    attn_kernel<<<BH_ * QBLK_, 256, 0, stream>>>(q, q + (size_t)BH_ * N_ * D_, v, attn, ctx);
  }
  {  // proj: [9232,768] x [768,768] + b_proj + x -> x1 fp32
    dim3 g(C_ / 64, (ROWS_ + 63) / 64, 1);
    gemm_kernel<3><<<g, 256, 0, stream>>>(ctx, C_, wproj_b, C_, ROWS_, C_, C_, x1,
                                          b_proj, x);
  }
  ln_kernel<<<ROWS_, 256, 0, stream>>>(x1, g2, be2, xn);
  {  // mlp1: [9232,768] x [768,3072] + b1, exact GELU -> h bf16
    dim3 g(HID_ / 64, (ROWS_ + 63) / 64, 1);
    gemm_kernel<4><<<g, 256, 0, stream>>>(xn, C_, w1_b, HID_, ROWS_, HID_, C_, h,
                                          b1, nullptr);
  }
  {  // mlp2: [9232,3072] x [3072,768] + b2 + x1 -> d_out (x part)
    dim3 g(C_ / 64, (ROWS_ + 63) / 64, 1);
    gemm_kernel<5><<<g, 256, 0, stream>>>(h, HID_, w2_b, C_, ROWS_, C_, HID_, out_x,
                                          b2, x1);
  }
}

// Round 4
// 487.261 us; speedup vs baseline: 2.4552x; 2.2422x over previous
//
#include <hip/hip_runtime.h>
#include <hip/hip_bf16.h>
#include <cmath>

// ---------------- problem constants ----------------
constexpr int B_ = 16, N_ = 577, C_ = 768, H_ = 12, D_ = 64, HID_ = 3072;
constexpr int ROWS_ = B_ * N_;   // 9232
constexpr int BH_ = B_ * H_;     // 192
constexpr int KVT_ = 10;         // kv tiles of 64
constexpr int QBLK_ = 10;        // q blocks of 64 per bh

typedef __attribute__((ext_vector_type(8))) __bf16 bf16x8;
typedef __attribute__((ext_vector_type(4))) float f32x4;
typedef __attribute__((ext_vector_type(4), aligned(4))) float f32x4u;

#define DEVI __device__ __forceinline__

DEVI unsigned short f2bf(float f) {
  unsigned u = __float_as_uint(f);
  return (unsigned short)((u + 0x7fffu + ((u >> 16) & 1u)) >> 16);
}
DEVI float bf2f(unsigned short u) { return __uint_as_float(((unsigned)u) << 16); }

DEVI void gload16(const void* src, void* dst) {
  __builtin_amdgcn_global_load_lds(
      (const __attribute__((address_space(1))) char*)src,
      (__attribute__((address_space(3))) char*)dst, 16, 0, 0);
}
#define VMCNT0 asm volatile("s_waitcnt vmcnt(0)" ::: "memory")

// ---------------- transpose + cvt: in [K][N] f32 -> out [N][K] bf16 ----------
__global__ __launch_bounds__(256) void cvtT_kernel(const float* __restrict__ in,
                                                   unsigned short* __restrict__ out,
                                                   int K, int N) {
  __shared__ float t[64][65];
  int n0 = blockIdx.x * 64, k0 = blockIdx.y * 64;
  int tx = threadIdx.x & 63, ty = threadIdx.x >> 6;
#pragma unroll
  for (int r = 0; r < 16; r++) {
    int kr = ty * 16 + r;
    t[kr][tx] = in[(long)(k0 + kr) * N + n0 + tx];
  }
  __syncthreads();
#pragma unroll
  for (int r = 0; r < 16; r++) {
    int nr = ty * 16 + r;
    out[(long)(n0 + nr) * K + k0 + tx] = f2bf(t[tx][nr]);
  }
}

// ---------------- layernorm (768 = 3*256) ----------------
__global__ __launch_bounds__(256) void ln_kernel(const float* __restrict__ x,
                                                 const float* __restrict__ g,
                                                 const float* __restrict__ be,
                                                 unsigned short* __restrict__ out) {
  int row = blockIdx.x;
  const float* xr = x + (long)row * C_;
  float v[3];
  float s = 0.f, s2 = 0.f;
#pragma unroll
  for (int j = 0; j < 3; j++) {
    int i = threadIdx.x + j * 256;
    v[j] = xr[i];
    s += v[j];
    s2 += v[j] * v[j];
  }
#pragma unroll
  for (int o = 32; o > 0; o >>= 1) {
    s += __shfl_down(s, o);
    s2 += __shfl_down(s2, o);
  }
  __shared__ float sh[8];
  int w = threadIdx.x >> 6;
  if ((threadIdx.x & 63) == 0) { sh[w] = s; sh[4 + w] = s2; }
  __syncthreads();
  s = sh[0] + sh[1] + sh[2] + sh[3];
  s2 = sh[4] + sh[5] + sh[6] + sh[7];
  float mu = s * (1.f / C_);
  float var = s2 * (1.f / C_) - mu * mu;
  float rs = rsqrtf(var + 1e-5f);
#pragma unroll
  for (int j = 0; j < 3; j++) {
    int i = threadIdx.x + j * 256;
    out[(long)row * C_ + i] = f2bf((v[j] - mu) * rs * g[i] + be[i]);
  }
}

// ---------------- fused attention ----------------
// q,k: [BH][N][D] bf16 (q pre-scaled); vt: [BH][D][N] bf16
// attn out: [BH][N][N] fp32 (nontemporal); ctx: [B][N][C] bf16
__global__ __launch_bounds__(256) void attn_kernel(
    const unsigned short* __restrict__ qg,
    const unsigned short* __restrict__ kg,
    const unsigned short* __restrict__ vt,
    float* __restrict__ attn,
    unsigned short* __restrict__ ctx) {
  __shared__ unsigned short KVs[2][2][64][64];  // [buf][K/V][row][col] (xor-swizzled)
  __shared__ unsigned short Ps[4][16][72];
  const int wgid = (blockIdx.x & 7) * (BH_ * QBLK_ / 8) + (blockIdx.x >> 3);
  const int bh = wgid / QBLK_, qb = wgid % QBLK_;
  const int b = bh / H_, h = bh % H_;
  const int tid = threadIdx.x, wave = tid >> 6, lane = tid & 63;
  const int l15 = lane & 15, l4 = lane >> 4;
  const int q0w = qb * 64 + wave * 16;

  const unsigned short* Qh = qg + (long)bh * N_ * D_;
  const char* Kb = (const char*)(kg + (long)bh * N_ * D_);
  const char* Vb = (const char*)(vt + (long)bh * D_ * N_);

  int qrc = q0w + l15; if (qrc >= N_) qrc = N_ - 1;
  bf16x8 qa0 = *(const bf16x8*)(Qh + (long)qrc * D_ + l4 * 8);
  bf16x8 qa1 = *(const bf16x8*)(Qh + (long)qrc * D_ + 32 + l4 * 8);

  // stage one 64x128B tile into KVs[buf][which], xor-swizzled source (G21)
  auto stage = [&](int buf, int which, const char* g0, int rstride) {
#pragma unroll
    for (int i = 0; i < 2; i++) {
      int off = i * 4096 + tid * 16;
      int row = off >> 7, colD = off & 127;
      const char* src = g0 + (long)row * rstride + (colD ^ ((row & 7) << 4));
      char* dst = ((char*)KVs) + buf * 16384 + which * 8192 + i * 4096 + wave * 1024;
      gload16(src, dst);
    }
  };
  auto rdKV = [&](int buf, int which, int row, int colb) -> bf16x8 {
    const char* p = ((const char*)KVs) + buf * 16384 + which * 8192 + row * 128 +
                    (colb ^ ((row & 7) << 4));
    return *(const bf16x8*)p;
  };
  auto computeS = [&](int buf, int kv0, f32x4 (&s)[4]) {
#pragma unroll
    for (int nf = 0; nf < 4; nf++) {
      int row = nf * 16 + l15;
      bf16x8 k0v = rdKV(buf, 0, row, l4 * 16);
      bf16x8 k1v = rdKV(buf, 0, row, 64 + l4 * 16);
      f32x4 z = {0.f, 0.f, 0.f, 0.f};
      z = __builtin_amdgcn_mfma_f32_16x16x32_bf16(qa0, k0v, z, 0, 0, 0);
      z = __builtin_amdgcn_mfma_f32_16x16x32_bf16(qa1, k1v, z, 0, 0, 0);
      if (kv0 + row >= N_) z = f32x4{-1e30f, -1e30f, -1e30f, -1e30f};
      s[nf] = z;
    }
  };

  // ---------- pass 1: per-lane online stats (no cross-lane until end) ----------
  float m_ln[4], l_ln[4];
#pragma unroll
  for (int r = 0; r < 4; r++) { m_ln[r] = -1e30f; l_ln[r] = 0.f; }

  stage(0, 0, Kb, 128);
  VMCNT0; __syncthreads();
  int buf = 0;
  for (int kt = 0; kt < KVT_; kt++) {
    if (kt + 1 < KVT_) stage(buf ^ 1, 0, Kb + (long)(kt + 1) * 8192, 128);
    f32x4 s[4];
    computeS(buf, kt * 64, s);
#pragma unroll
    for (int r = 0; r < 4; r++) {
      float t0 = fmaxf(fmaxf(s[0][r], s[1][r]), fmaxf(s[2][r], s[3][r]));
      float mn = fmaxf(m_ln[r], t0);
      float sc = __expf(m_ln[r] - mn);
      l_ln[r] = l_ln[r] * sc + __expf(s[0][r] - mn) + __expf(s[1][r] - mn) +
                __expf(s[2][r] - mn) + __expf(s[3][r] - mn);
      m_ln[r] = mn;
    }
    VMCNT0; __syncthreads();
    buf ^= 1;
  }

  float m_run[4], inv_l[4];
#pragma unroll
  for (int r = 0; r < 4; r++) {
    float m = m_ln[r];
#pragma unroll
    for (int o = 1; o < 16; o <<= 1) m = fmaxf(m, __shfl_xor(m, o));
    float li = l_ln[r] * __expf(m_ln[r] - m);
#pragma unroll
    for (int o = 1; o < 16; o <<= 1) li += __shfl_xor(li, o);
    m_run[r] = m;
    inv_l[r] = 1.f / li;
  }

  // ---------- pass 2: P emit + PV ----------
  f32x4 cacc[4];
#pragma unroll
  for (int nf = 0; nf < 4; nf++) cacc[nf] = f32x4{0.f, 0.f, 0.f, 0.f};

  stage(0, 0, Kb, 128);
  stage(0, 1, Vb, N_ * 2);
  VMCNT0; __syncthreads();
  buf = 0;
  for (int kt = 0; kt < KVT_; kt++) {
    const int kv0 = kt * 64;
    if (kt + 1 < KVT_) {
      stage(buf ^ 1, 0, Kb + (long)(kt + 1) * 8192, 128);
      stage(buf ^ 1, 1, Vb + (long)(kt + 1) * 128, N_ * 2);
    }
    f32x4 s[4];
    computeS(buf, kv0, s);
#pragma unroll
    for (int nf = 0; nf < 4; nf++)
#pragma unroll
      for (int r = 0; r < 4; r++) {
        float p = __expf(s[nf][r] - m_run[r]) * inv_l[r];
        Ps[wave][l4 * 4 + r][nf * 16 + l15] = f2bf(p);
      }
    // vectorized nontemporal fp32 P store (4 dwordx4 per lane-role per kt)
    if (kt < KVT_ - 1) {
      int prow = lane >> 4;
      int c0 = (lane & 15) * 4;
#pragma unroll
      for (int rg = 0; rg < 4; rg++) {
        int row = rg * 4 + prow;
        int qv = q0w + row;
        if (qv < N_) {
          ushort4 pb = *(const ushort4*)&Ps[wave][row][c0];
          f32x4u f;
          f[0] = bf2f(pb.x); f[1] = bf2f(pb.y); f[2] = bf2f(pb.z); f[3] = bf2f(pb.w);
          __builtin_nontemporal_store(
              f, (f32x4u*)(attn + ((long)bh * N_ + qv) * N_ + kv0 + c0));
        }
      }
    } else {  // kv0 = 576: single valid column
      if ((lane & 15) == 0) {
        int prow = lane >> 4;
#pragma unroll
        for (int rg = 0; rg < 4; rg++) {
          int row = rg * 4 + prow;
          int qv = q0w + row;
          if (qv < N_)
            __builtin_nontemporal_store(bf2f(Ps[wave][row][0]),
                                        attn + ((long)bh * N_ + qv) * N_ + 576);
        }
      }
    }
    // PV from LDS V tile
#pragma unroll
    for (int ks = 0; ks < 2; ks++) {
      bf16x8 pa = *(const bf16x8*)&Ps[wave][l15][ks * 32 + l4 * 8];
#pragma unroll
      for (int nf = 0; nf < 4; nf++) {
        bf16x8 vb = rdKV(buf, 1, nf * 16 + l15, ks * 64 + l4 * 16);
        cacc[nf] = __builtin_amdgcn_mfma_f32_16x16x32_bf16(pa, vb, cacc[nf], 0, 0, 0);
      }
    }
    VMCNT0; __syncthreads();
    buf ^= 1;
  }

  // ---------- ctx write ----------
#pragma unroll
  for (int nf = 0; nf < 4; nf++)
#pragma unroll
    for (int r = 0; r < 4; r++) {
      int qv = q0w + l4 * 4 + r;
      if (qv >= N_) continue;
      int d = nf * 16 + l15;
      ctx[((long)b * N_ + qv) * C_ + h * D_ + d] = f2bf(cacc[nf][r]);
    }
}

// ---------------- 128x128 MFMA GEMM, BK=64, global_load_lds, dbuf ----------------
// A: [M][K] bf16; BT: [N][K] bf16 (k-major). N = gridDim.x*128 (multiple of 128).
// EPI: 0 qkv scatter | 3/5 f32 +bias+resid | 4 bf16 gelu(+bias)
template <int EPI>
__global__ __launch_bounds__(256) void gemm128(
    const unsigned short* __restrict__ A,
    const unsigned short* __restrict__ BT,
    int M, int K, int Nc,
    void* __restrict__ outp, const float* __restrict__ bias,
    const float* __restrict__ resid) {
  __shared__ unsigned short As[2][128][64];
  __shared__ unsigned short Bs[2][128][64];
  const int tid = threadIdx.x, wave = tid >> 6, lane = tid & 63;
  const int l15 = lane & 15, l4 = lane >> 4;
  const long m0 = (long)blockIdx.y * 128, n0 = (long)blockIdx.x * 128;
  const int wr = (wave >> 1) * 64, wc = (wave & 1) * 64;

  f32x4 acc[4][4];
#pragma unroll
  for (int i = 0; i < 4; i++)
#pragma unroll
    for (int j = 0; j < 4; j++) acc[i][j] = f32x4{0.f, 0.f, 0.f, 0.f};

  auto stageA = [&](int buf, int t) {
#pragma unroll
    for (int i = 0; i < 4; i++) {
      int off = i * 4096 + tid * 16;
      int row = off >> 7, colD = off & 127;
      long gr = m0 + row; if (gr >= M) gr = M - 1;
      const char* src = (const char*)A + (gr * (long)K + (long)t * 64) * 2 +
                        (colD ^ ((row & 7) << 4));
      char* dst = ((char*)As) + buf * 16384 + i * 4096 + wave * 1024;
      gload16(src, dst);
    }
  };
  auto stageB = [&](int buf, int t) {
#pragma unroll
    for (int i = 0; i < 4; i++) {
      int off = i * 4096 + tid * 16;
      int row = off >> 7, colD = off & 127;
      const char* src = (const char*)BT + ((n0 + row) * (long)K + (long)t * 64) * 2 +
                        (colD ^ ((row & 7) << 4));
      char* dst = ((char*)Bs) + buf * 16384 + i * 4096 + wave * 1024;
      gload16(src, dst);
    }
  };

  const int nt = K / 64;
  stageA(0, 0); stageB(0, 0);
  VMCNT0; __syncthreads();
  int buf = 0;
  for (int t = 0; t < nt; t++) {
    if (t + 1 < nt) { stageA(buf ^ 1, t + 1); stageB(buf ^ 1, t + 1); }
    bf16x8 af[4][2], bfr[4][2];
#pragma unroll
    for (int mf = 0; mf < 4; mf++)
#pragma unroll
      for (int kk = 0; kk < 2; kk++) {
        int row = wr + mf * 16 + l15, colb = kk * 64 + l4 * 16;
        af[mf][kk] = *(const bf16x8*)(((const char*)As) + buf * 16384 + row * 128 +
                                      (colb ^ ((row & 7) << 4)));
      }
#pragma unroll
    for (int nf = 0; nf < 4; nf++)
#pragma unroll
      for (int kk = 0; kk < 2; kk++) {
        int row = wc + nf * 16 + l15, colb = kk * 64 + l4 * 16;
        bfr[nf][kk] = *(const bf16x8*)(((const char*)Bs) + buf * 16384 + row * 128 +
                                       (colb ^ ((row & 7) << 4)));
      }
#pragma unroll
    for (int kk = 0; kk < 2; kk++)
#pragma unroll
      for (int mf = 0; mf < 4; mf++)
#pragma unroll
        for (int nf = 0; nf < 4; nf++)
          acc[mf][nf] =
              __builtin_amdgcn_mfma_f32_16x16x32_bf16(af[mf][kk], bfr[nf][kk], acc[mf][nf], 0, 0, 0);
    VMCNT0; __syncthreads();
    buf ^= 1;
  }

  // ---- epilogue ----
#pragma unroll
  for (int mf = 0; mf < 4; mf++)
#pragma unroll
    for (int nf = 0; nf < 4; nf++)
#pragma unroll
      for (int r = 0; r < 4; r++) {
        long row = m0 + wr + mf * 16 + l4 * 4 + r;
        long col = n0 + wc + nf * 16 + l15;
        if (row >= M) continue;
        float v = acc[mf][nf][r];
        if constexpr (EPI == 0) {
          v += bias[col];
          int which = (int)col / C_;
          int rem = (int)col % C_;
          int hh = rem >> 6, d = rem & 63;
          int bb = (int)row / N_, n = (int)row % N_;
          if (which == 0) v *= 0.125f;
          unsigned short* o = (unsigned short*)outp;
          long base = (long)which * ((long)BH_ * N_ * D_);
          long idx;
          if (which < 2)
            idx = base + (((long)(bb * H_ + hh)) * N_ + n) * D_ + d;  // q,k: [BH][N][D]
          else
            idx = base + (((long)(bb * H_ + hh)) * D_ + d) * N_ + n;  // v: [BH][D][N]
          o[idx] = f2bf(v);
        } else if constexpr (EPI == 3 || EPI == 5) {
          float* o = (float*)outp;
          long idx = row * (long)Nc + col;
          o[idx] = v + bias[col] + resid[idx];
        } else if constexpr (EPI == 4) {
          v += bias[col];
          float ge = 0.5f * v * (1.f + erff(v * 0.70710678118654752f));
          ((unsigned short*)outp)[row * (long)Nc + col] = f2bf(ge);
        }
      }
}

// ---------------- launch ----------------
extern "C" void kernel_launch(void* const* d_in, const int* in_sizes, int n_in,
                              void* d_out, int out_size, void* d_ws, size_t ws_size,
                              hipStream_t stream) {
  const float* x = (const float*)d_in[0];
  const float* w_qkv = (const float*)d_in[1];
  const float* b_qkv = (const float*)d_in[2];
  const float* w_proj = (const float*)d_in[3];
  const float* b_proj = (const float*)d_in[4];
  const float* g1 = (const float*)d_in[5];
  const float* be1 = (const float*)d_in[6];
  const float* g2 = (const float*)d_in[7];
  const float* be2 = (const float*)d_in[8];
  const float* w1 = (const float*)d_in[9];
  const float* b1 = (const float*)d_in[10];
  const float* w2 = (const float*)d_in[11];
  const float* b2 = (const float*)d_in[12];

  char* ws = (char*)d_ws;
  const size_t SZ_TOK_BF = (size_t)ROWS_ * C_ * 2;
  unsigned short* xn = (unsigned short*)(ws);
  unsigned short* q = (unsigned short*)(ws + SZ_TOK_BF);      // [BH][N][D]
  unsigned short* v = (unsigned short*)(ws + 3 * SZ_TOK_BF);  // [BH][D][N]
  unsigned short* ctx = (unsigned short*)(ws + 4 * SZ_TOK_BF);
  unsigned short* hbuf = q;  // reuse q/k/v/ctx area for MLP hidden
  float* x1 = (float*)(ws + 5 * SZ_TOK_BF);
  unsigned short* wqkvT = (unsigned short*)(ws + 5 * SZ_TOK_BF + (size_t)ROWS_ * C_ * 4);
  unsigned short* wprojT = wqkvT + (size_t)C_ * 3 * C_;
  unsigned short* w1T = wprojT + (size_t)C_ * C_;
  unsigned short* w2T = w1T + (size_t)C_ * HID_;

  float* out_x = (float*)d_out;
  float* attn = out_x + (size_t)ROWS_ * C_;

  // transpose+cvt weights to [N][K] bf16
  cvtT_kernel<<<dim3(3 * C_ / 64, C_ / 64), 256, 0, stream>>>(w_qkv, wqkvT, C_, 3 * C_);
  cvtT_kernel<<<dim3(C_ / 64, C_ / 64), 256, 0, stream>>>(w_proj, wprojT, C_, C_);
  cvtT_kernel<<<dim3(HID_ / 64, C_ / 64), 256, 0, stream>>>(w1, w1T, C_, HID_);
  cvtT_kernel<<<dim3(C_ / 64, HID_ / 64), 256, 0, stream>>>(w2, w2T, HID_, C_);

  ln_kernel<<<ROWS_, 256, 0, stream>>>(x, g1, be1, xn);

  {  // QKV
    dim3 g(3 * C_ / 128, (ROWS_ + 127) / 128);
    gemm128<0><<<g, 256, 0, stream>>>(xn, wqkvT, ROWS_, C_, 3 * C_, q, b_qkv, nullptr);
  }
  attn_kernel<<<BH_ * QBLK_, 256, 0, stream>>>(q, q + (size_t)BH_ * N_ * D_, v, attn, ctx);
  {  // proj + residual
    dim3 g(C_ / 128, (ROWS_ + 127) / 128);
    gemm128<3><<<g, 256, 0, stream>>>(ctx, wprojT, ROWS_, C_, C_, x1, b_proj, x);
  }
  ln_kernel<<<ROWS_, 256, 0, stream>>>(x1, g2, be2, xn);
  {  // mlp1 + gelu
    dim3 g(HID_ / 128, (ROWS_ + 127) / 128);
    gemm128<4><<<g, 256, 0, stream>>>(xn, w1T, ROWS_, C_, HID_, hbuf, b1, nullptr);
  }
  {  // mlp2 + residual -> out_x
    dim3 g(C_ / 128, (ROWS_ + 127) / 128);
    gemm128<5><<<g, 256, 0, stream>>>(hbuf, w2T, ROWS_, HID_, C_, out_x, b2, x1);
  }
}